// Round 5
// baseline (381.475 us; speedup 1.0000x reference)
//
#include <hip/hip_runtime.h>
#include <hip/hip_cooperative_groups.h>
#include <math.h>

namespace cg = cooperative_groups;

#define T    512        // threads per block (8 waves)
#define BMAX 512        // grid blocks for mega kernel
#define BSH  7          // bucket shift: 128 nodes per bucket
#define BSZ  128
#define D    128

// =================== cooperative mega-kernel ===================
__global__ __launch_bounds__(T, 4) void mega(
    const float* __restrict__ x, const int* __restrict__ src, const int* __restrict__ dst,
    const float* __restrict__ W1, const float* __restrict__ b1,
    const float* __restrict__ W2, const float* __restrict__ b2,
    const float2* __restrict__ noise, float2* __restrict__ out,
    int* __restrict__ hist_t, int* __restrict__ dsum, int* __restrict__ bstart,
    unsigned* __restrict__ pairs, float4* __restrict__ zd, float4* __restrict__ aw,
    float* __restrict__ W12, float* __restrict__ cvec,
    int N, int E, int NB)
{
    cg::grid_group grid = cg::this_grid();
    const int B = gridDim.x;
    const int t = threadIdx.x;
    const int b = blockIdx.x;

    __shared__ int   cnt[T];
    __shared__ int   cur[T];
    __shared__ float accf[BSZ * 4];

    const bool quadOK = ((E & 3) == 0);   // dst = ei+E must stay 16B-aligned
    const int  nq = E >> 2;
    const int  cq = (nq + B - 1) / B;

    // ---------------- P1: bucket histogram (+ W12/cvec on block 0) ----------------
    for (int i = t; i < NB; i += T) cnt[i] = 0;
    __syncthreads();
    if (quadOK) {
        const int4* dst4 = (const int4*)dst;
        int lo = b * cq, hi = min(nq, lo + cq);
        for (int i = lo + t; i < hi; i += T) {
            int4 dv = dst4[i];
            atomicAdd(&cnt[dv.x >> BSH], 1);
            atomicAdd(&cnt[dv.y >> BSH], 1);
            atomicAdd(&cnt[dv.z >> BSH], 1);
            atomicAdd(&cnt[dv.w >> BSH], 1);
        }
    } else {
        int ce = (E + B - 1) / B;
        int lo = b * ce, hi = min(E, lo + ce);
        for (int i = lo + t; i < hi; i += T) atomicAdd(&cnt[dst[i] >> BSH], 1);
    }
    __syncthreads();
    for (int i = t; i < NB; i += T) hist_t[i * B + b] = cnt[i];
    if (b == 0) {
        if (t < 256) {
            int k = t >> 1, c = t & 1;
            float acc = 0.f;
            for (int m = 0; m < D; ++m) acc += W1[k * D + m] * W2[m * 2 + c];
            W12[t] = acc;           // index k*2+c == t
        }
        if (t < 2) {
            float s = 0.f;
            for (int m = 0; m < D; ++m) s += b1[m] * W2[m * 2 + t];
            cvec[t] = s;
        }
    }
    grid.sync();

    // ---------------- P2: per-digit exclusive scan over B block-counts ----------------
    for (int d = b; d < NB; d += B) {
        int v = (t < B) ? hist_t[d * B + t] : 0;
        cnt[t] = v;
        __syncthreads();
        for (int o = 1; o < T; o <<= 1) {
            int add = (t >= o) ? cnt[t - o] : 0;
            __syncthreads();
            cnt[t] += add;
            __syncthreads();
        }
        if (t < B) hist_t[d * B + t] = cnt[t] - v;
        if (t == T - 1) dsum[d] = cnt[T - 1];
        __syncthreads();
    }
    grid.sync();

    // ---------------- P3: local bstart scan + pair scatter ----------------
    {
        int v = (t < NB) ? dsum[t] : 0;
        cnt[t] = v;
        __syncthreads();
        for (int o = 1; o < T; o <<= 1) {
            int add = (t >= o) ? cnt[t - o] : 0;
            __syncthreads();
            cnt[t] += add;
            __syncthreads();
        }
        int excl = cnt[t] - v;                 // bucket start for digit t
        if (b == 0) {
            if (t < NB) bstart[t] = excl;
            if (t == 0) bstart[NB] = E;
        }
        if (t < NB) cur[t] = hist_t[t * B + b] + excl;
        __syncthreads();
        if (quadOK) {
            const int4* dst4 = (const int4*)dst;
            const int4* src4 = (const int4*)src;
            int lo = b * cq, hi = min(nq, lo + cq);
            for (int i = lo + t; i < hi; i += T) {
                int4 dv = dst4[i];
                int4 sv = src4[i];
                int p0 = atomicAdd(&cur[dv.x >> BSH], 1);
                pairs[p0] = ((unsigned)(dv.x & (BSZ - 1)) << 16) | (unsigned)sv.x;
                int p1 = atomicAdd(&cur[dv.y >> BSH], 1);
                pairs[p1] = ((unsigned)(dv.y & (BSZ - 1)) << 16) | (unsigned)sv.y;
                int p2 = atomicAdd(&cur[dv.z >> BSH], 1);
                pairs[p2] = ((unsigned)(dv.z & (BSZ - 1)) << 16) | (unsigned)sv.z;
                int p3 = atomicAdd(&cur[dv.w >> BSH], 1);
                pairs[p3] = ((unsigned)(dv.w & (BSZ - 1)) << 16) | (unsigned)sv.w;
            }
        } else {
            int ce = (E + B - 1) / B;
            int lo = b * ce, hi = min(E, lo + ce);
            for (int i = lo + t; i < hi; i += T) {
                int d = dst[i];
                int p = atomicAdd(&cur[d >> BSH], 1);
                pairs[p] = ((unsigned)(d & (BSZ - 1)) << 16) | (unsigned)src[i];
            }
        }
    }
    grid.sync();

    // ---------------- P4: per-bucket degree -> dinv (zd.z); then z = x@W12 (zd.xy) ----------------
    for (int bb = b; bb < NB; bb += B) {
        int bs = bstart[bb], be = bstart[bb + 1];
        for (int i = t; i < BSZ; i += T) cnt[i] = 0;
        __syncthreads();
        for (int i = bs + t; i < be; i += T) atomicAdd(&cnt[pairs[i] >> 16], 1);
        __syncthreads();
        if (t < BSZ) {
            int node = (bb << BSH) + t;
            if (node < N) zd[node].z = rsqrtf((float)(cnt[t] + 1));
        }
        __syncthreads();
    }
    {
        int wave = t >> 6, lane = t & 63;
        int nwaves = B * (T >> 6);
        int wid = b * (T >> 6) + wave;
        float4 wv = *(const float4*)(W12 + lane * 4);   // uniform per lane
        for (int node = wid; node < N; node += nwaves) {
            float2 xv = *(const float2*)(x + (size_t)node * D + lane * 2);
            float p0 = xv.x * wv.x + xv.y * wv.z;
            float p1 = xv.x * wv.y + xv.y * wv.w;
#pragma unroll
            for (int o = 32; o > 0; o >>= 1) {
                p0 += __shfl_xor(p0, o);
                p1 += __shfl_xor(p1, o);
            }
            if (lane == 0) {
                float2 r; r.x = p0; r.y = p1;
                *(float2*)&zd[node] = r;                // writes .x,.y only
            }
        }
    }
    grid.sync();

    // ---------------- P5: gather A per bucket -> aw = (dinv*a1, srow, dinv) ----------------
    for (int bb = b; bb < NB; bb += B) {
        int bs = bstart[bb], be = bstart[bb + 1];
        for (int i = t; i < BSZ * 4; i += T) accf[i] = 0.f;
        __syncthreads();
        for (int i = bs + t; i < be; i += T) {
            unsigned p = pairs[i];
            int s   = p & 0xFFFFu;
            int low = p >> 16;
            float4 zv = zd[s];                          // (z.x, z.y, dinv, -)
            atomicAdd(&accf[low * 4 + 0], zv.z * zv.x);
            atomicAdd(&accf[low * 4 + 1], zv.z * zv.y);
            atomicAdd(&accf[low * 4 + 2], zv.z);
        }
        __syncthreads();
        if (t < BSZ) {
            int node = (bb << BSH) + t;
            if (node < N) {
                float4 zv = zd[node];
                float wd = zv.z;
                float a1x  = wd * (accf[t * 4 + 0] + wd * zv.x);
                float a1y  = wd * (accf[t * 4 + 1] + wd * zv.y);
                float srow = wd * (accf[t * 4 + 2] + wd);
                float4 r;
                r.x = wd * a1x; r.y = wd * a1y; r.z = srow; r.w = wd;
                aw[node] = r;
            }
        }
        __syncthreads();
    }
    grid.sync();

    // ---------------- P6: gather B per bucket + gumbel softmax epilogue ----------------
    for (int bb = b; bb < NB; bb += B) {
        int bs = bstart[bb], be = bstart[bb + 1];
        for (int i = t; i < BSZ * 4; i += T) accf[i] = 0.f;
        __syncthreads();
        for (int i = bs + t; i < be; i += T) {
            unsigned p = pairs[i];
            int s   = p & 0xFFFFu;
            int low = p >> 16;
            float4 av = aw[s];                          // (dinv*a1, srow, dinv)
            atomicAdd(&accf[low * 4 + 0], av.x);
            atomicAdd(&accf[low * 4 + 1], av.y);
        }
        __syncthreads();
        if (t < BSZ) {
            int node = (bb << BSH) + t;
            if (node < N) {
                float4 av = aw[node];
                float wd = av.w;
                float l0 = wd * (accf[t * 4 + 0] + av.x) + av.z * cvec[0] + b2[0];
                float l1 = wd * (accf[t * 4 + 1] + av.y) + av.z * cvec[1] + b2[1];
                const float EPS = 1e-9f;
                float2 nv = noise[node];
                float g0 = -logf(-logf(nv.x + EPS) + EPS);
                float g1 = -logf(-logf(nv.y + EPS) + EPS);
                float u0 = (l0 + g0) * 2.0f;
                float u1 = (l1 + g1) * 2.0f;
                float m = fmaxf(u0, u1);
                float e0 = __expf(u0 - m), e1 = __expf(u1 - m);
                float inv = 1.0f / (e0 + e1);
                float2 r; r.x = e0 * inv; r.y = e1 * inv;
                out[node] = r;
            }
        }
        __syncthreads();
    }
}

// =================== fallback path (round-4 pipeline) ===================
#define FB1 512
__global__ void k_hist(const int* __restrict__ dst, int* __restrict__ hist_t, int E) {
    __shared__ int h[256];
    h[threadIdx.x] = 0;
    __syncthreads();
    int chunk = (E + gridDim.x - 1) / gridDim.x;
    int lo = blockIdx.x * chunk, hi = min(E, lo + chunk);
    for (int i = lo + threadIdx.x; i < hi; i += 256)
        atomicAdd(&h[dst[i] >> 8], 1);
    __syncthreads();
    hist_t[threadIdx.x * gridDim.x + blockIdx.x] = h[threadIdx.x];
}
__global__ void k_scan_digit(int* __restrict__ hist_t, int* __restrict__ dsum) {
    __shared__ int s[256];
    int d = blockIdx.x, t = threadIdx.x;
    int i0 = d * FB1 + 2 * t;
    int a = hist_t[i0], b = hist_t[i0 + 1];
    s[t] = a + b;
    __syncthreads();
    for (int o = 1; o < 256; o <<= 1) {
        int add = (t >= o) ? s[t - o] : 0;
        __syncthreads(); s[t] += add; __syncthreads();
    }
    int excl = s[t] - (a + b);
    hist_t[i0] = excl; hist_t[i0 + 1] = excl + a;
    if (t == 255) dsum[d] = s[255];
}
__global__ void k_scan_bstart(const int* __restrict__ dsum, int* __restrict__ bstart, int E) {
    __shared__ int s[256];
    int t = threadIdx.x;
    int v = dsum[t];
    s[t] = v;
    __syncthreads();
    for (int o = 1; o < 256; o <<= 1) {
        int add = (t >= o) ? s[t - o] : 0;
        __syncthreads(); s[t] += add; __syncthreads();
    }
    bstart[t] = s[t] - v;
    if (t == 255) bstart[256] = E;
}
__global__ void k_scatter_pairs(const int* __restrict__ src, const int* __restrict__ dst,
                                const int* __restrict__ hist_t, const int* __restrict__ bstart,
                                unsigned* __restrict__ pairs, int E) {
    __shared__ int cur[256];
    cur[threadIdx.x] = hist_t[threadIdx.x * gridDim.x + blockIdx.x] + bstart[threadIdx.x];
    __syncthreads();
    int chunk = (E + gridDim.x - 1) / gridDim.x;
    int lo = blockIdx.x * chunk, hi = min(E, lo + chunk);
    for (int i = lo + threadIdx.x; i < hi; i += 256) {
        int d = dst[i];
        int p = atomicAdd(&cur[d >> 8], 1);
        pairs[p] = ((unsigned)(d & 255) << 16) | (unsigned)src[i];
    }
}
__global__ void k_bucket_csr(const unsigned* __restrict__ pairs, const int* __restrict__ bucket_start,
                             int* __restrict__ csr, int* __restrict__ rowstart,
                             int* __restrict__ deg, float* __restrict__ dinv, int N) {
    int b = blockIdx.x;
    int bs = bucket_start[b], be = bucket_start[b + 1];
    __shared__ int h[256];
    __shared__ int rs[256];
    int t = threadIdx.x;
    if (t < 256) h[t] = 0;
    __syncthreads();
    for (int i = bs + t; i < be; i += 1024) atomicAdd(&h[pairs[i] >> 16], 1);
    __syncthreads();
    int v = 0;
    if (t < 256) { v = h[t]; rs[t] = v; }
    __syncthreads();
    for (int o = 1; o < 256; o <<= 1) {
        int add = (t < 256 && t >= o) ? rs[t - o] : 0;
        __syncthreads();
        if (t < 256) rs[t] += add;
        __syncthreads();
    }
    if (t < 256) {
        int excl = rs[t] - v;
        int node = (b << 8) + t;
        if (node < N) {
            rowstart[node] = bs + excl;
            deg[node] = v;
            dinv[node] = rsqrtf((float)(v + 1));
        }
        h[t] = excl;
    }
    __syncthreads();
    for (int i = bs + t; i < be; i += 1024) {
        unsigned p = pairs[i];
        int pos = bs + atomicAdd(&h[p >> 16], 1);
        csr[pos] = (int)(p & 0xFFFFu);
    }
}
__global__ void k_w12(const float* __restrict__ W1, const float* __restrict__ W2,
                      const float* __restrict__ b1, float* __restrict__ W12,
                      float* __restrict__ cvec) {
    int t = threadIdx.x;
    int k = t >> 1, c = t & 1;
    float acc = 0.f;
    for (int m = 0; m < D; ++m) acc += W1[k * D + m] * W2[m * 2 + c];
    W12[k * 2 + c] = acc;
    if (t < 2) {
        float s = 0.f;
        for (int m = 0; m < D; ++m) s += b1[m] * W2[m * 2 + t];
        cvec[t] = s;
    }
}
__global__ void k_z(const float* __restrict__ x, const float* __restrict__ W12,
                    float2* __restrict__ z, int N) {
    int gid = blockIdx.x * blockDim.x + threadIdx.x;
    int node = gid >> 6;
    int lane = threadIdx.x & 63;
    if (node >= N) return;
    float2 xv = *(const float2*)(x + (size_t)node * D + lane * 2);
    float4 wv = *(const float4*)(W12 + lane * 4);
    float p0 = xv.x * wv.x + xv.y * wv.z;
    float p1 = xv.x * wv.y + xv.y * wv.w;
#pragma unroll
    for (int o = 32; o > 0; o >>= 1) { p0 += __shfl_xor(p0, o); p1 += __shfl_xor(p1, o); }
    if (lane == 0) { float2 r; r.x = p0; r.y = p1; z[node] = r; }
}
__global__ void k_gatherA(const int* __restrict__ csr, const int* __restrict__ rowstart,
                          const int* __restrict__ deg, const float* __restrict__ dinv,
                          const float2* __restrict__ z, float2* __restrict__ a1,
                          float* __restrict__ srow, int N) {
    int g = blockIdx.x * blockDim.x + threadIdx.x;
    int node = g >> 4, lane = threadIdx.x & 15;
    if (node >= N) return;
    int rs = rowstart[node], dg = deg[node];
    float acc0 = 0.f, acc1 = 0.f, sw = 0.f;
    for (int j = lane; j < dg; j += 16) {
        int s = csr[rs + j];
        float w = dinv[s];
        float2 zv = z[s];
        acc0 += w * zv.x; acc1 += w * zv.y; sw += w;
    }
#pragma unroll
    for (int o = 8; o > 0; o >>= 1) {
        acc0 += __shfl_xor(acc0, o); acc1 += __shfl_xor(acc1, o); sw += __shfl_xor(sw, o);
    }
    if (lane == 0) {
        float wd = dinv[node], wd2 = wd * wd;
        float2 zv = z[node];
        float2 r; r.x = wd * acc0 + wd2 * zv.x; r.y = wd * acc1 + wd2 * zv.y;
        a1[node] = r;
        srow[node] = wd * sw + wd2;
    }
}
__global__ void k_gatherB(const int* __restrict__ csr, const int* __restrict__ rowstart,
                          const int* __restrict__ deg, const float* __restrict__ dinv,
                          const float2* __restrict__ a1, const float* __restrict__ srow,
                          const float* __restrict__ cvec, const float* __restrict__ b2,
                          const float2* __restrict__ noise, float2* __restrict__ out, int N) {
    int g = blockIdx.x * blockDim.x + threadIdx.x;
    int node = g >> 4, lane = threadIdx.x & 15;
    if (node >= N) return;
    int rs = rowstart[node], dg = deg[node];
    float acc0 = 0.f, acc1 = 0.f;
    for (int j = lane; j < dg; j += 16) {
        int s = csr[rs + j];
        float w = dinv[s];
        float2 av = a1[s];
        acc0 += w * av.x; acc1 += w * av.y;
    }
#pragma unroll
    for (int o = 8; o > 0; o >>= 1) { acc0 += __shfl_xor(acc0, o); acc1 += __shfl_xor(acc1, o); }
    if (lane == 0) {
        const float EPS = 1e-9f;
        float wd = dinv[node], wd2 = wd * wd;
        float2 av = a1[node];
        float sr = srow[node];
        float l0 = wd * acc0 + wd2 * av.x + sr * cvec[0] + b2[0];
        float l1 = wd * acc1 + wd2 * av.y + sr * cvec[1] + b2[1];
        float2 nv = noise[node];
        float g0 = -logf(-logf(nv.x + EPS) + EPS);
        float g1 = -logf(-logf(nv.y + EPS) + EPS);
        float u0 = (l0 + g0) * 2.0f, u1 = (l1 + g1) * 2.0f;
        float m = fmaxf(u0, u1);
        float e0 = __expf(u0 - m), e1 = __expf(u1 - m);
        float inv = 1.0f / (e0 + e1);
        float2 r; r.x = e0 * inv; r.y = e1 * inv;
        out[node] = r;
    }
}

extern "C" void kernel_launch(void* const* d_in, const int* in_sizes, int n_in,
                              void* d_out, int out_size, void* d_ws, size_t ws_size,
                              hipStream_t stream) {
    const float* x     = (const float*)d_in[0];
    const int*   ei    = (const int*)d_in[1];
    const float* W1    = (const float*)d_in[2];
    const float* b1    = (const float*)d_in[3];
    const float* W2    = (const float*)d_in[4];
    const float* b2    = (const float*)d_in[5];
    const float* noise = (const float*)d_in[6];
    float* out = (float*)d_out;

    const int N = in_sizes[0] / D;
    const int E = in_sizes[1] / 2;
    const int* src = ei;
    const int* dst = ei + E;
    const int NB = (N + BSZ - 1) >> BSH;      // buckets of 128 nodes

    // ---- workspace carve (16B-aligned chunks first) ----
    char* p = (char*)d_ws;
    float4*   zd     = (float4*)p;   p += (size_t)N * 16;
    float4*   aw     = (float4*)p;   p += (size_t)N * 16;
    unsigned* pairs  = (unsigned*)p; p += (size_t)E * 4;
    int*      hist_t = (int*)p;      p += (size_t)512 * BMAX * 4;
    int*      dsum   = (int*)p;      p += 512 * 4;
    int*      bstart = (int*)p;      p += 516 * 4;
    float*    W12    = (float*)p;    p += 256 * 4;
    float*    cvec   = (float*)p;    p += 16;

    int Ni = N, Ei = E, NBi = NB;
    void* args[] = {
        (void*)&x, (void*)&src, (void*)&dst, (void*)&W1, (void*)&b1,
        (void*)&W2, (void*)&b2, (void*)&noise, (void*)&out,
        (void*)&hist_t, (void*)&dsum, (void*)&bstart, (void*)&pairs,
        (void*)&zd, (void*)&aw, (void*)&W12, (void*)&cvec,
        (void*)&Ni, (void*)&Ei, (void*)&NBi
    };
    hipError_t err = hipLaunchCooperativeKernel((const void*)mega, dim3(BMAX), dim3(T),
                                                args, 0, stream);
    if (err == hipSuccess) return;

    // ---- fallback: round-4 multi-kernel pipeline (256-node buckets) ----
    (void)hipGetLastError();   // clear error state
    char* q = (char*)d_ws;
    float* z2        = (float*)q; q += (size_t)N * 8;
    float* a12       = (float*)q; q += (size_t)N * 8;
    unsigned* pairs2 = (unsigned*)q; q += (size_t)E * 4;
    int*   csr2      = (int*)q;   q += (size_t)E * 4;
    int*   rowstart2 = (int*)q;   q += (size_t)N * 4;
    int*   deg2      = (int*)q;   q += (size_t)N * 4;
    float* dinv2     = (float*)q; q += (size_t)N * 4;
    float* srow2     = (float*)q; q += (size_t)N * 4;
    int*   hist2     = (int*)q;   q += (size_t)256 * FB1 * 4;
    int*   dsum2     = (int*)q;   q += 256 * 4;
    int*   bstart2   = (int*)q;   q += 260 * 4;
    float* W122      = (float*)q; q += 256 * 4;
    float* cvec2     = (float*)q; q += 16;

    int nbuckets = (N + 255) / 256;
    int gZ  = (N + 3) / 4;
    int g16 = (N * 16 + 255) / 256;

    k_hist<<<FB1, 256, 0, stream>>>(dst, hist2, E);
    k_scan_digit<<<256, 256, 0, stream>>>(hist2, dsum2);
    k_scan_bstart<<<1, 256, 0, stream>>>(dsum2, bstart2, E);
    k_scatter_pairs<<<FB1, 256, 0, stream>>>(src, dst, hist2, bstart2, pairs2, E);
    k_w12<<<1, 256, 0, stream>>>(W1, W2, b1, W122, cvec2);
    k_bucket_csr<<<nbuckets, 1024, 0, stream>>>(pairs2, bstart2, csr2, rowstart2, deg2, dinv2, N);
    k_z<<<gZ, 256, 0, stream>>>(x, W122, (float2*)z2, N);
    k_gatherA<<<g16, 256, 0, stream>>>(csr2, rowstart2, deg2, dinv2, (const float2*)z2,
                                       (float2*)a12, srow2, N);
    k_gatherB<<<g16, 256, 0, stream>>>(csr2, rowstart2, deg2, dinv2, (const float2*)a12,
                                       srow2, cvec2, b2, (const float2*)noise,
                                       (float2*)out, N);
}

// Round 6
// 105.441 us; speedup vs baseline: 3.6179x; 3.6179x over previous
//
#include <hip/hip_runtime.h>
#include <math.h>

#define D    128
#define BSH  7          // 128 nodes per bucket
#define BSZ  128
#define GB1  512        // blocks for hist/scatter passes
#define KT   512        // threads per block everywhere

// ---- K1: bucket histogram of dst>>7 (digit-major table) + W12/cvec on block 0 ----
__global__ void k_hist(const int* __restrict__ dst, int* __restrict__ hist_t,
                       const float* __restrict__ W1, const float* __restrict__ b1,
                       const float* __restrict__ W2,
                       float* __restrict__ W12, float* __restrict__ cvec,
                       int E, int NB) {
    __shared__ int   h[512];
    __shared__ float wtmp[512];
    int t = threadIdx.x, b = blockIdx.x, B = gridDim.x;
    for (int i = t; i < NB; i += KT) h[i] = 0;
    __syncthreads();
    if ((E & 3) == 0) {
        const int4* dst4 = (const int4*)dst;
        int nq = E >> 2;
        int cq = (nq + B - 1) / B;
        int lo = b * cq, hi = min(nq, lo + cq);
        for (int i = lo + t; i < hi; i += KT) {
            int4 dv = dst4[i];
            atomicAdd(&h[dv.x >> BSH], 1);
            atomicAdd(&h[dv.y >> BSH], 1);
            atomicAdd(&h[dv.z >> BSH], 1);
            atomicAdd(&h[dv.w >> BSH], 1);
        }
    } else {
        int ce = (E + B - 1) / B;
        int lo = b * ce, hi = min(E, lo + ce);
        for (int i = lo + t; i < hi; i += KT) atomicAdd(&h[dst[i] >> BSH], 1);
    }
    __syncthreads();
    for (int i = t; i < NB; i += KT) hist_t[i * B + b] = h[i];
    if (b == 0) {
        // W12 = W1@W2 (256 outputs), split each 128-dot across 2 threads
        int idx = t >> 1, half = t & 1;       // idx in [0,256)
        int k = idx >> 1, c = idx & 1;
        float acc = 0.f;
        int m0 = half * 64;
        for (int m = m0; m < m0 + 64; ++m) acc += W1[k * D + m] * W2[m * 2 + c];
        wtmp[t] = acc;
        __syncthreads();
        if (half == 0) W12[idx] = wtmp[t] + wtmp[t + 1];
        if (t < 2) {
            float s = 0.f;
            for (int m = 0; m < D; ++m) s += b1[m] * W2[m * 2 + t];
            cvec[t] = s;
        }
    }
}

// ---- K2: per-digit exclusive scan over its GB1 block-counts ----
__global__ void k_scan_digit(int* __restrict__ hist_t, int* __restrict__ dsum) {
    __shared__ int s[KT];
    int d = blockIdx.x, t = threadIdx.x;
    int v = hist_t[d * GB1 + t];
    s[t] = v;
    __syncthreads();
    for (int o = 1; o < KT; o <<= 1) {
        int add = (t >= o) ? s[t - o] : 0;
        __syncthreads();
        s[t] += add;
        __syncthreads();
    }
    hist_t[d * GB1 + t] = s[t] - v;
    if (t == KT - 1) dsum[d] = s[KT - 1];
}

// ---- K3: exclusive scan of digit totals -> bucket starts ----
__global__ void k_scan_bstart(const int* __restrict__ dsum, int* __restrict__ bstart,
                              int E, int NB) {
    __shared__ int s[KT];
    int t = threadIdx.x;
    int v = (t < NB) ? dsum[t] : 0;
    s[t] = v;
    __syncthreads();
    for (int o = 1; o < KT; o <<= 1) {
        int add = (t >= o) ? s[t - o] : 0;
        __syncthreads();
        s[t] += add;
        __syncthreads();
    }
    if (t < NB) bstart[t] = s[t] - v;
    if (t == 0) bstart[NB] = E;
}

// ---- K4: route edges into buckets; pairs = (node_local<<25) | src ----
__global__ void k_scatter_pairs(const int* __restrict__ src, const int* __restrict__ dst,
                                const int* __restrict__ hist_t, const int* __restrict__ bstart,
                                unsigned* __restrict__ pairs, int E, int NB) {
    __shared__ int cur[512];
    int t = threadIdx.x, b = blockIdx.x, B = gridDim.x;
    for (int i = t; i < NB; i += KT) cur[i] = hist_t[i * B + b] + bstart[i];
    __syncthreads();
    if ((E & 3) == 0) {
        const int4* dst4 = (const int4*)dst;
        const int4* src4 = (const int4*)src;
        int nq = E >> 2;
        int cq = (nq + B - 1) / B;
        int lo = b * cq, hi = min(nq, lo + cq);
        for (int i = lo + t; i < hi; i += KT) {
            int4 dv = dst4[i];
            int4 sv = src4[i];
            int p0 = atomicAdd(&cur[dv.x >> BSH], 1);
            pairs[p0] = ((unsigned)(dv.x & (BSZ - 1)) << 25) | (unsigned)sv.x;
            int p1 = atomicAdd(&cur[dv.y >> BSH], 1);
            pairs[p1] = ((unsigned)(dv.y & (BSZ - 1)) << 25) | (unsigned)sv.y;
            int p2 = atomicAdd(&cur[dv.z >> BSH], 1);
            pairs[p2] = ((unsigned)(dv.z & (BSZ - 1)) << 25) | (unsigned)sv.z;
            int p3 = atomicAdd(&cur[dv.w >> BSH], 1);
            pairs[p3] = ((unsigned)(dv.w & (BSZ - 1)) << 25) | (unsigned)sv.w;
        }
    } else {
        int ce = (E + B - 1) / B;
        int lo = b * ce, hi = min(E, lo + ce);
        for (int i = lo + t; i < hi; i += KT) {
            int d = dst[i];
            int p = atomicAdd(&cur[d >> BSH], 1);
            pairs[p] = ((unsigned)(d & (BSZ - 1)) << 25) | (unsigned)src[i];
        }
    }
}

// ---- K5: per-bucket degree -> dinv (zd.z); then z = x@W12 -> (zd.x, zd.y) ----
__global__ void k_zdinv(const unsigned* __restrict__ pairs, const int* __restrict__ bstart,
                        const float* __restrict__ x, const float* __restrict__ W12,
                        float4* __restrict__ zd, int N, int NB) {
    __shared__ int cnt[BSZ];
    int t = threadIdx.x, b = blockIdx.x, B = gridDim.x;
    for (int bb = b; bb < NB; bb += B) {
        int bs = bstart[bb], be = bstart[bb + 1];
        if (t < BSZ) cnt[t] = 0;
        __syncthreads();
        for (int i = bs + t; i < be; i += KT) atomicAdd(&cnt[pairs[i] >> 25], 1);
        __syncthreads();
        if (t < BSZ) {
            int node = (bb << BSH) + t;
            if (node < N) zd[node].z = rsqrtf((float)(cnt[t] + 1));
        }
        __syncthreads();
    }
    // z = x @ W12, one wave per node row (disjoint bytes from .z writes above)
    int wave = t >> 6, lane = t & 63;
    int nwaves = B * (KT >> 6);
    int wid = b * (KT >> 6) + wave;
    float4 wv = *(const float4*)(W12 + lane * 4);
    for (int node = wid; node < N; node += nwaves) {
        float2 xv = *(const float2*)(x + (size_t)node * D + lane * 2);
        float p0 = fmaf(xv.x, wv.x, xv.y * wv.z);
        float p1 = fmaf(xv.x, wv.y, xv.y * wv.w);
#pragma unroll
        for (int o = 32; o > 0; o >>= 1) {
            p0 += __shfl_xor(p0, o);
            p1 += __shfl_xor(p1, o);
        }
        if (lane == 0) {
            float2 r; r.x = p0; r.y = p1;
            *(float2*)&zd[node] = r;
        }
    }
}

// ---- K6: gather A per bucket -> aw = (dinv*a1x, dinv*a1y, srow, dinv) ----
__global__ void k_gatherA(const unsigned* __restrict__ pairs, const int* __restrict__ bstart,
                          const float4* __restrict__ zd, float4* __restrict__ aw, int N) {
    __shared__ float accf[BSZ * 4];
    int t = threadIdx.x, bb = blockIdx.x;
    int bs = bstart[bb], be = bstart[bb + 1];
    for (int i = t; i < BSZ * 4; i += KT) accf[i] = 0.f;
    __syncthreads();
    for (int i = bs + t; i < be; i += KT) {
        unsigned p = pairs[i];
        int s = p & 0x1FFFFFF, low = p >> 25;
        float4 zv = zd[s];                       // (z0, z1, dinv, -)
        atomicAdd(&accf[low * 4 + 0], zv.z * zv.x);
        atomicAdd(&accf[low * 4 + 1], zv.z * zv.y);
        atomicAdd(&accf[low * 4 + 2], zv.z);
    }
    __syncthreads();
    if (t < BSZ) {
        int node = (bb << BSH) + t;
        if (node < N) {
            float4 zv = zd[node];
            float wd = zv.z;
            float a1x  = wd * (accf[t * 4 + 0] + wd * zv.x);
            float a1y  = wd * (accf[t * 4 + 1] + wd * zv.y);
            float srow = wd * (accf[t * 4 + 2] + wd);
            aw[node] = make_float4(wd * a1x, wd * a1y, srow, wd);
        }
    }
}

// ---- K7: gather B per bucket + rank-1 bias + gumbel softmax epilogue ----
__global__ void k_gatherB(const unsigned* __restrict__ pairs, const int* __restrict__ bstart,
                          const float4* __restrict__ aw, const float* __restrict__ cvec,
                          const float* __restrict__ b2, const float2* __restrict__ noise,
                          float2* __restrict__ out, int N) {
    __shared__ float accf[BSZ * 2];
    int t = threadIdx.x, bb = blockIdx.x;
    int bs = bstart[bb], be = bstart[bb + 1];
    for (int i = t; i < BSZ * 2; i += KT) accf[i] = 0.f;
    __syncthreads();
    for (int i = bs + t; i < be; i += KT) {
        unsigned p = pairs[i];
        int s = p & 0x1FFFFFF, low = p >> 25;
        float4 av = aw[s];                       // (w*a1x, w*a1y, srow, w)
        atomicAdd(&accf[low * 2 + 0], av.x);
        atomicAdd(&accf[low * 2 + 1], av.y);
    }
    __syncthreads();
    if (t < BSZ) {
        int node = (bb << BSH) + t;
        if (node < N) {
            float4 av = aw[node];
            float wd = av.w;
            float l0 = wd * (accf[t * 2 + 0] + av.x) + av.z * cvec[0] + b2[0];
            float l1 = wd * (accf[t * 2 + 1] + av.y) + av.z * cvec[1] + b2[1];
            const float EPS = 1e-9f;
            float2 nv = noise[node];
            float g0 = -logf(-logf(nv.x + EPS) + EPS);
            float g1 = -logf(-logf(nv.y + EPS) + EPS);
            float u0 = (l0 + g0) * 2.0f;
            float u1 = (l1 + g1) * 2.0f;
            float m = fmaxf(u0, u1);
            float e0 = __expf(u0 - m), e1 = __expf(u1 - m);
            float inv = 1.0f / (e0 + e1);
            float2 r; r.x = e0 * inv; r.y = e1 * inv;
            out[node] = r;
        }
    }
}

extern "C" void kernel_launch(void* const* d_in, const int* in_sizes, int n_in,
                              void* d_out, int out_size, void* d_ws, size_t ws_size,
                              hipStream_t stream) {
    const float* x     = (const float*)d_in[0];
    const int*   ei    = (const int*)d_in[1];
    const float* W1    = (const float*)d_in[2];
    const float* b1    = (const float*)d_in[3];
    const float* W2    = (const float*)d_in[4];
    const float* b2    = (const float*)d_in[5];
    const float* noise = (const float*)d_in[6];
    float* out = (float*)d_out;

    const int N = in_sizes[0] / D;
    const int E = in_sizes[1] / 2;
    const int* src = ei;
    const int* dst = ei + E;
    const int NB = (N + BSZ - 1) >> BSH;       // 391 buckets of 128 nodes

    // ---- workspace carve (16B-aligned chunks first) ----
    char* p = (char*)d_ws;
    float4*   zd     = (float4*)p;   p += (size_t)N * 16;
    float4*   aw     = (float4*)p;   p += (size_t)N * 16;
    unsigned* pairs  = (unsigned*)p; p += (size_t)E * 4;
    int*      hist_t = (int*)p;      p += (size_t)512 * GB1 * 4;   // 1 MB
    int*      dsum   = (int*)p;      p += 512 * 4;
    int*      bstart = (int*)p;      p += 520 * 4;
    float*    W12    = (float*)p;    p += 256 * 4;
    float*    cvec   = (float*)p;    p += 16;

    k_hist<<<GB1, KT, 0, stream>>>(dst, hist_t, W1, b1, W2, W12, cvec, E, NB);
    k_scan_digit<<<NB, KT, 0, stream>>>(hist_t, dsum);
    k_scan_bstart<<<1, KT, 0, stream>>>(dsum, bstart, E, NB);
    k_scatter_pairs<<<GB1, KT, 0, stream>>>(src, dst, hist_t, bstart, pairs, E, NB);
    k_zdinv<<<GB1, KT, 0, stream>>>(pairs, bstart, x, W12, zd, N, NB);
    k_gatherA<<<NB, KT, 0, stream>>>(pairs, bstart, zd, aw, N);
    k_gatherB<<<NB, KT, 0, stream>>>(pairs, bstart, aw, cvec, b2, (const float2*)noise,
                                     (float2*)out, N);
}

// Round 7
// 73.721 us; speedup vs baseline: 5.1746x; 1.4303x over previous
//
#include <hip/hip_runtime.h>
#include <math.h>

#define D    128
#define BSH  7          // 128 nodes per bucket
#define BSZ  128
#define GB1  512        // blocks for hist/scatter passes (== scan row length)
#define KT   512        // threads per block for sort kernels

// ---- K1: bucket histogram of dst>>7 (digit-major table) + W12/cvec on block 0 ----
__global__ void k_hist(const int* __restrict__ dst, int* __restrict__ hist_t,
                       const float* __restrict__ W1, const float* __restrict__ b1,
                       const float* __restrict__ W2,
                       float* __restrict__ W12, float* __restrict__ cvec,
                       int E, int NB) {
    __shared__ int   h[512];
    __shared__ float wtmp[512];
    int t = threadIdx.x, b = blockIdx.x, B = gridDim.x;
    for (int i = t; i < NB; i += KT) h[i] = 0;
    __syncthreads();
    if ((E & 3) == 0) {
        const int4* dst4 = (const int4*)dst;
        int nq = E >> 2;
        int cq = (nq + B - 1) / B;
        int lo = b * cq, hi = min(nq, lo + cq);
        for (int i = lo + t; i < hi; i += KT) {
            int4 dv = dst4[i];
            atomicAdd(&h[dv.x >> BSH], 1);
            atomicAdd(&h[dv.y >> BSH], 1);
            atomicAdd(&h[dv.z >> BSH], 1);
            atomicAdd(&h[dv.w >> BSH], 1);
        }
    } else {
        int ce = (E + B - 1) / B;
        int lo = b * ce, hi = min(E, lo + ce);
        for (int i = lo + t; i < hi; i += KT) atomicAdd(&h[dst[i] >> BSH], 1);
    }
    __syncthreads();
    for (int i = t; i < NB; i += KT) hist_t[i * B + b] = h[i];
    if (b == 0) {
        int idx = t >> 1, half = t & 1;       // idx in [0,256)
        int k = idx >> 1, c = idx & 1;
        float acc = 0.f;
        int m0 = half * 64;
        for (int m = m0; m < m0 + 64; ++m) acc += W1[k * D + m] * W2[m * 2 + c];
        wtmp[t] = acc;
        __syncthreads();
        if (half == 0) W12[idx] = wtmp[t] + wtmp[t + 1];
        if (t < 2) {
            float s = 0.f;
            for (int m = 0; m < D; ++m) s += b1[m] * W2[m * 2 + t];
            cvec[t] = s;
        }
    }
}

// ---- K2: per-digit exclusive scan over GB1 block-counts (wave-scan, 2 barriers) ----
__global__ void k_scan_digit(int* __restrict__ hist_t, int* __restrict__ dsum) {
    __shared__ int wtot[8];
    int d = blockIdx.x, t = threadIdx.x, lane = t & 63, w = t >> 6;
    int v = hist_t[d * GB1 + t];
    int inc = v;
#pragma unroll
    for (int o = 1; o < 64; o <<= 1) {
        int n = __shfl_up(inc, o);
        if (lane >= o) inc += n;
    }
    if (lane == 63) wtot[w] = inc;
    __syncthreads();
    if (t < 8) {
        int x = wtot[t];
#pragma unroll
        for (int o = 1; o < 8; o <<= 1) {
            int n = __shfl_up(x, o, 8);
            if (t >= o) x += n;
        }
        wtot[t] = x;   // inclusive wave totals
    }
    __syncthreads();
    int woff = (w == 0) ? 0 : wtot[w - 1];
    hist_t[d * GB1 + t] = woff + inc - v;     // exclusive
    if (t == KT - 1) dsum[d] = wtot[7];
}

// ---- K3: exclusive scan of digit totals -> bucket starts; sentinels ----
__global__ void k_scan_bstart(const int* __restrict__ dsum, int* __restrict__ bstart,
                              int* __restrict__ rowstart, int E, int NB, int N) {
    __shared__ int wtot[8];
    int t = threadIdx.x, lane = t & 63, w = t >> 6;
    int v = (t < NB) ? dsum[t] : 0;
    int inc = v;
#pragma unroll
    for (int o = 1; o < 64; o <<= 1) {
        int n = __shfl_up(inc, o);
        if (lane >= o) inc += n;
    }
    if (lane == 63) wtot[w] = inc;
    __syncthreads();
    if (t < 8) {
        int x = wtot[t];
#pragma unroll
        for (int o = 1; o < 8; o <<= 1) {
            int n = __shfl_up(x, o, 8);
            if (t >= o) x += n;
        }
        wtot[t] = x;
    }
    __syncthreads();
    int woff = (w == 0) ? 0 : wtot[w - 1];
    if (t < NB) bstart[t] = woff + inc - v;
    if (t == 0) { bstart[NB] = E; rowstart[N] = E; }
}

// ---- K4: route edges into buckets; pairs = (node_local<<20) | src ----
__global__ void k_scatter_pairs(const int* __restrict__ src, const int* __restrict__ dst,
                                const int* __restrict__ hist_t, const int* __restrict__ bstart,
                                unsigned* __restrict__ pairs, int E, int NB) {
    __shared__ int cur[512];
    int t = threadIdx.x, b = blockIdx.x, B = gridDim.x;
    for (int i = t; i < NB; i += KT) cur[i] = hist_t[i * B + b] + bstart[i];
    __syncthreads();
    if ((E & 3) == 0) {
        const int4* dst4 = (const int4*)dst;
        const int4* src4 = (const int4*)src;
        int nq = E >> 2;
        int cq = (nq + B - 1) / B;
        int lo = b * cq, hi = min(nq, lo + cq);
        for (int i = lo + t; i < hi; i += KT) {
            int4 dv = dst4[i];
            int4 sv = src4[i];
            int p0 = atomicAdd(&cur[dv.x >> BSH], 1);
            pairs[p0] = ((unsigned)(dv.x & (BSZ - 1)) << 20) | (unsigned)sv.x;
            int p1 = atomicAdd(&cur[dv.y >> BSH], 1);
            pairs[p1] = ((unsigned)(dv.y & (BSZ - 1)) << 20) | (unsigned)sv.y;
            int p2 = atomicAdd(&cur[dv.z >> BSH], 1);
            pairs[p2] = ((unsigned)(dv.z & (BSZ - 1)) << 20) | (unsigned)sv.z;
            int p3 = atomicAdd(&cur[dv.w >> BSH], 1);
            pairs[p3] = ((unsigned)(dv.w & (BSZ - 1)) << 20) | (unsigned)sv.w;
        }
    } else {
        int ce = (E + B - 1) / B;
        int lo = b * ce, hi = min(E, lo + ce);
        for (int i = lo + t; i < hi; i += KT) {
            int d = dst[i];
            int p = atomicAdd(&cur[d >> BSH], 1);
            pairs[p] = ((unsigned)(d & (BSZ - 1)) << 20) | (unsigned)src[i];
        }
    }
}

// ---- K5: per-bucket node-sort -> csr + rowstart + dinv(zd.z); then z = x@W12 (zd.xy) ----
__global__ void k_csr_z(const unsigned* __restrict__ pairs, const int* __restrict__ bstart,
                        const float* __restrict__ x, const float* __restrict__ W12,
                        int* __restrict__ csr, int* __restrict__ rowstart,
                        float4* __restrict__ zd, int N, int NB) {
    __shared__ int h[BSZ];
    __shared__ int wtot2[2];
    int t = threadIdx.x, b = blockIdx.x, B = gridDim.x;
    int lane = t & 63, w = t >> 6;
    for (int bb = b; bb < NB; bb += B) {
        int bs = bstart[bb], be = bstart[bb + 1];
        if (t < BSZ) h[t] = 0;
        __syncthreads();
        for (int i = bs + t; i < be; i += KT) atomicAdd(&h[pairs[i] >> 20], 1);
        __syncthreads();
        int v = 0, inc = 0;
        if (t < BSZ) {
            v = h[t];
            inc = v;
#pragma unroll
            for (int o = 1; o < 64; o <<= 1) {
                int n = __shfl_up(inc, o);
                if (lane >= o) inc += n;
            }
            if (lane == 63) wtot2[w] = inc;
        }
        __syncthreads();
        if (t < BSZ) {
            int excl = ((w == 1) ? wtot2[0] : 0) + inc - v;
            int node = (bb << BSH) + t;
            if (node <= N) rowstart[node] = bs + excl;
            if (node < N)  zd[node].z = rsqrtf((float)(v + 1));
            h[t] = excl;                       // bucket-relative cursor
        }
        __syncthreads();
        for (int i = bs + t; i < be; i += KT) {
            unsigned p = pairs[i];
            int pos = bs + atomicAdd(&h[p >> 20], 1);
            csr[pos] = (int)(p & 0xFFFFFu);
        }
        __syncthreads();
    }
    // ---- z = x @ W12, one wave per node row ----
    int nwaves = B * (KT >> 6);
    int wid = b * (KT >> 6) + w;
    float4 wv = *(const float4*)(W12 + lane * 4);
    for (int node = wid; node < N; node += nwaves) {
        float2 xv = *(const float2*)(x + (size_t)node * D + lane * 2);
        float p0 = fmaf(xv.x, wv.x, xv.y * wv.z);
        float p1 = fmaf(xv.x, wv.y, xv.y * wv.w);
#pragma unroll
        for (int o = 32; o > 0; o >>= 1) {
            p0 += __shfl_xor(p0, o);
            p1 += __shfl_xor(p1, o);
        }
        if (lane == 0) {
            float2 r; r.x = p0; r.y = p1;
            *(float2*)&zd[node] = r;           // writes .x,.y only (.z disjoint)
        }
    }
}

// ---- K6: gather A (16 lanes/node, register acc) -> aw = (w*a1x, w*a1y, srow, w) ----
__global__ void k_gatherA(const int* __restrict__ csr, const int* __restrict__ rowstart,
                          const float4* __restrict__ zd, float4* __restrict__ aw, int N) {
    int g = blockIdx.x * blockDim.x + threadIdx.x;
    int node = g >> 4, lane = threadIdx.x & 15;
    if (node >= N) return;
    int rs = rowstart[node], re = rowstart[node + 1];
    float acc0 = 0.f, acc1 = 0.f, sw = 0.f;
    for (int j = rs + lane; j < re; j += 16) {
        int s = csr[j];
        float4 zv = zd[s];                     // (z0, z1, dinv, -)
        acc0 = fmaf(zv.z, zv.x, acc0);
        acc1 = fmaf(zv.z, zv.y, acc1);
        sw  += zv.z;
    }
#pragma unroll
    for (int o = 8; o > 0; o >>= 1) {
        acc0 += __shfl_xor(acc0, o);
        acc1 += __shfl_xor(acc1, o);
        sw   += __shfl_xor(sw, o);
    }
    if (lane == 0) {
        float4 zv = zd[node];
        float wd = zv.z;
        float a1x  = wd * (acc0 + wd * zv.x);
        float a1y  = wd * (acc1 + wd * zv.y);
        float srow = wd * (sw + wd);
        aw[node] = make_float4(wd * a1x, wd * a1y, srow, wd);
    }
}

// ---- K7: gather B (16 lanes/node) + rank-1 bias + gumbel softmax epilogue ----
__global__ void k_gatherB(const int* __restrict__ csr, const int* __restrict__ rowstart,
                          const float4* __restrict__ aw, const float* __restrict__ cvec,
                          const float* __restrict__ b2, const float2* __restrict__ noise,
                          float2* __restrict__ out, int N) {
    int g = blockIdx.x * blockDim.x + threadIdx.x;
    int node = g >> 4, lane = threadIdx.x & 15;
    if (node >= N) return;
    int rs = rowstart[node], re = rowstart[node + 1];
    float acc0 = 0.f, acc1 = 0.f;
    for (int j = rs + lane; j < re; j += 16) {
        int s = csr[j];
        float4 av = aw[s];                     // (w*a1x, w*a1y, srow, w)
        acc0 += av.x;
        acc1 += av.y;
    }
#pragma unroll
    for (int o = 8; o > 0; o >>= 1) {
        acc0 += __shfl_xor(acc0, o);
        acc1 += __shfl_xor(acc1, o);
    }
    if (lane == 0) {
        float4 av = aw[node];
        float wd = av.w;
        float l0 = wd * (acc0 + av.x) + av.z * cvec[0] + b2[0];
        float l1 = wd * (acc1 + av.y) + av.z * cvec[1] + b2[1];
        const float EPS = 1e-9f;
        float2 nv = noise[node];
        float g0 = -logf(-logf(nv.x + EPS) + EPS);
        float g1 = -logf(-logf(nv.y + EPS) + EPS);
        float u0 = (l0 + g0) * 2.0f;
        float u1 = (l1 + g1) * 2.0f;
        float m = fmaxf(u0, u1);
        float e0 = __expf(u0 - m), e1 = __expf(u1 - m);
        float inv = 1.0f / (e0 + e1);
        float2 r; r.x = e0 * inv; r.y = e1 * inv;
        out[node] = r;
    }
}

extern "C" void kernel_launch(void* const* d_in, const int* in_sizes, int n_in,
                              void* d_out, int out_size, void* d_ws, size_t ws_size,
                              hipStream_t stream) {
    const float* x     = (const float*)d_in[0];
    const int*   ei    = (const int*)d_in[1];
    const float* W1    = (const float*)d_in[2];
    const float* b1    = (const float*)d_in[3];
    const float* W2    = (const float*)d_in[4];
    const float* b2    = (const float*)d_in[5];
    const float* noise = (const float*)d_in[6];
    float* out = (float*)d_out;

    const int N = in_sizes[0] / D;
    const int E = in_sizes[1] / 2;
    const int* src = ei;
    const int* dst = ei + E;
    const int NB = (N + BSZ - 1) >> BSH;       // buckets of 128 nodes (<=512)

    // ---- workspace carve (16B-aligned chunks first) ----
    char* p = (char*)d_ws;
    float4*   zd     = (float4*)p;   p += (size_t)N * 16;
    float4*   aw     = (float4*)p;   p += (size_t)N * 16;
    unsigned* pairs  = (unsigned*)p; p += (size_t)E * 4;
    int*      csr    = (int*)p;      p += (size_t)E * 4;
    int*      rowstart = (int*)p;    p += (size_t)(N + 4) * 4;
    int*      hist_t = (int*)p;      p += (size_t)512 * GB1 * 4;   // 1 MB
    int*      dsum   = (int*)p;      p += 512 * 4;
    int*      bstart = (int*)p;      p += 520 * 4;
    float*    W12    = (float*)p;    p += 256 * 4;
    float*    cvec   = (float*)p;    p += 16;

    int g16 = (N * 16 + 255) / 256;            // 16 lanes/node, 256-thr blocks

    k_hist<<<GB1, KT, 0, stream>>>(dst, hist_t, W1, b1, W2, W12, cvec, E, NB);
    k_scan_digit<<<NB, KT, 0, stream>>>(hist_t, dsum);
    k_scan_bstart<<<1, KT, 0, stream>>>(dsum, bstart, rowstart, E, NB, N);
    k_scatter_pairs<<<GB1, KT, 0, stream>>>(src, dst, hist_t, bstart, pairs, E, NB);
    k_csr_z<<<1024, KT, 0, stream>>>(pairs, bstart, x, W12, csr, rowstart, zd, N, NB);
    k_gatherA<<<g16, 256, 0, stream>>>(csr, rowstart, zd, aw, N);
    k_gatherB<<<g16, 256, 0, stream>>>(csr, rowstart, aw, cvec, b2, (const float2*)noise,
                                       (float2*)out, N);
}

// Round 8
// 71.484 us; speedup vs baseline: 5.3365x; 1.0313x over previous
//
#include <hip/hip_runtime.h>
#include <math.h>

#define D    128
#define BSH  7          // 128 nodes per bucket
#define BSZ  128
#define GB1  512        // blocks for hist/scatter passes (== scan row length)
#define KT   512        // threads per block for sort kernels
#define STAGE_CAP 8192  // LDS staging capacity (edges) in k_csr_z

// ---- K1: bucket histogram of dst>>7 (digit-major table) + W12/cvec on block 0 ----
__global__ void k_hist(const int* __restrict__ dst, int* __restrict__ hist_t,
                       const float* __restrict__ W1, const float* __restrict__ b1,
                       const float* __restrict__ W2,
                       float* __restrict__ W12, float* __restrict__ cvec,
                       int E, int NB) {
    __shared__ int   h[512];
    __shared__ float wtmp[512];
    int t = threadIdx.x, b = blockIdx.x, B = gridDim.x;
    for (int i = t; i < NB; i += KT) h[i] = 0;
    __syncthreads();
    if ((E & 3) == 0) {
        const int4* dst4 = (const int4*)dst;
        int nq = E >> 2;
        int cq = (nq + B - 1) / B;
        int lo = b * cq, hi = min(nq, lo + cq);
        for (int i = lo + t; i < hi; i += KT) {
            int4 dv = dst4[i];
            atomicAdd(&h[dv.x >> BSH], 1);
            atomicAdd(&h[dv.y >> BSH], 1);
            atomicAdd(&h[dv.z >> BSH], 1);
            atomicAdd(&h[dv.w >> BSH], 1);
        }
    } else {
        int ce = (E + B - 1) / B;
        int lo = b * ce, hi = min(E, lo + ce);
        for (int i = lo + t; i < hi; i += KT) atomicAdd(&h[dst[i] >> BSH], 1);
    }
    __syncthreads();
    for (int i = t; i < NB; i += KT) hist_t[i * B + b] = h[i];
    if (b == 0) {
        int idx = t >> 1, half = t & 1;       // idx in [0,256)
        int k = idx >> 1, c = idx & 1;
        float acc = 0.f;
        int m0 = half * 64;
        for (int m = m0; m < m0 + 64; ++m) acc += W1[k * D + m] * W2[m * 2 + c];
        wtmp[t] = acc;
        __syncthreads();
        if (half == 0) W12[idx] = wtmp[t] + wtmp[t + 1];
        if (t < 2) {
            float s = 0.f;
            for (int m = 0; m < D; ++m) s += b1[m] * W2[m * 2 + t];
            cvec[t] = s;
        }
    }
}

// ---- K2: per-digit exclusive scan over GB1 block-counts; dsum; rowstart[N]=E ----
__global__ void k_scan_digit(int* __restrict__ hist_t, int* __restrict__ dsum,
                             int* __restrict__ rowstart, int N, int E) {
    __shared__ int wtot[8];
    int d = blockIdx.x, t = threadIdx.x, lane = t & 63, w = t >> 6;
    int v = hist_t[d * GB1 + t];
    int inc = v;
#pragma unroll
    for (int o = 1; o < 64; o <<= 1) {
        int n = __shfl_up(inc, o);
        if (lane >= o) inc += n;
    }
    if (lane == 63) wtot[w] = inc;
    __syncthreads();
    if (t < 8) {
        int x = wtot[t];
#pragma unroll
        for (int o = 1; o < 8; o <<= 1) {
            int n = __shfl_up(x, o, 8);
            if (t >= o) x += n;
        }
        wtot[t] = x;   // inclusive wave totals
    }
    __syncthreads();
    int woff = (w == 0) ? 0 : wtot[w - 1];
    hist_t[d * GB1 + t] = woff + inc - v;     // exclusive
    if (t == KT - 1) dsum[d] = wtot[7];
    if (d == 0 && t == 0) rowstart[N] = E;    // sentinel (no dependency)
}

// helper: in-block exclusive scan of dsum[0..NB) across 512 threads -> returns excl for t
__device__ __forceinline__ int block_scan_dsum(const int* __restrict__ dsum, int NB,
                                               int* wtot /*shared[8]*/) {
    int t = threadIdx.x, lane = t & 63, w = t >> 6;
    int v = (t < NB) ? dsum[t] : 0;
    int inc = v;
#pragma unroll
    for (int o = 1; o < 64; o <<= 1) {
        int n = __shfl_up(inc, o);
        if (lane >= o) inc += n;
    }
    if (lane == 63) wtot[w] = inc;
    __syncthreads();
    if (t < 8) {
        int x = wtot[t];
#pragma unroll
        for (int o = 1; o < 8; o <<= 1) {
            int n = __shfl_up(x, o, 8);
            if (t >= o) x += n;
        }
        wtot[t] = x;
    }
    __syncthreads();
    int woff = (w == 0) ? 0 : wtot[w - 1];
    return woff + inc - v;
}

// ---- K3: route edges into buckets (in-block bucket-start scan from dsum) ----
__global__ void k_scatter_pairs(const int* __restrict__ src, const int* __restrict__ dst,
                                const int* __restrict__ hist_t, const int* __restrict__ dsum,
                                unsigned* __restrict__ pairs, int E, int NB) {
    __shared__ int cur[512];
    __shared__ int wtot[8];
    int t = threadIdx.x, b = blockIdx.x, B = gridDim.x;
    int bsti = block_scan_dsum(dsum, NB, wtot);
    if (t < NB) cur[t] = hist_t[t * B + b] + bsti;
    __syncthreads();
    if ((E & 3) == 0) {
        const int4* dst4 = (const int4*)dst;
        const int4* src4 = (const int4*)src;
        int nq = E >> 2;
        int cq = (nq + B - 1) / B;
        int lo = b * cq, hi = min(nq, lo + cq);
        for (int i = lo + t; i < hi; i += KT) {
            int4 dv = dst4[i];
            int4 sv = src4[i];
            int p0 = atomicAdd(&cur[dv.x >> BSH], 1);
            pairs[p0] = ((unsigned)(dv.x & (BSZ - 1)) << 20) | (unsigned)sv.x;
            int p1 = atomicAdd(&cur[dv.y >> BSH], 1);
            pairs[p1] = ((unsigned)(dv.y & (BSZ - 1)) << 20) | (unsigned)sv.y;
            int p2 = atomicAdd(&cur[dv.z >> BSH], 1);
            pairs[p2] = ((unsigned)(dv.z & (BSZ - 1)) << 20) | (unsigned)sv.z;
            int p3 = atomicAdd(&cur[dv.w >> BSH], 1);
            pairs[p3] = ((unsigned)(dv.w & (BSZ - 1)) << 20) | (unsigned)sv.w;
        }
    } else {
        int ce = (E + B - 1) / B;
        int lo = b * ce, hi = min(E, lo + ce);
        for (int i = lo + t; i < hi; i += KT) {
            int d = dst[i];
            int p = atomicAdd(&cur[d >> BSH], 1);
            pairs[p] = ((unsigned)(d & (BSZ - 1)) << 20) | (unsigned)src[i];
        }
    }
}

// ---- K4: per-bucket node-sort (LDS-staged) -> csr + rowstart + dinv(zd.z); z = x@W12 ----
__global__ __launch_bounds__(KT) void k_csr_z(
        const unsigned* __restrict__ pairs, const int* __restrict__ dsum,
        const float* __restrict__ x, const float* __restrict__ W12,
        int* __restrict__ csr, int* __restrict__ rowstart,
        float4* __restrict__ zd, int N, int E, int NB) {
    __shared__ unsigned stage[STAGE_CAP];
    __shared__ int bst[512];
    __shared__ int h[BSZ];
    __shared__ int wtot[8];
    int t = threadIdx.x, b = blockIdx.x, B = gridDim.x;
    int lane = t & 63, w = t >> 6;

    int bsti = block_scan_dsum(dsum, NB, wtot);
    bst[t] = bsti;
    __syncthreads();

    for (int bb = b; bb < NB; bb += B) {
        int bs = bst[bb];
        int be = (bb + 1 < NB) ? bst[bb + 1] : E;
        int ne = be - bs;
        if (t < BSZ) h[t] = 0;
        __syncthreads();
        bool fits = (ne <= STAGE_CAP);
        if (fits) {
            for (int i = t; i < ne; i += KT) {
                unsigned p = pairs[bs + i];
                stage[i] = p;
                atomicAdd(&h[p >> 20], 1);
            }
        } else {
            for (int i = t; i < ne; i += KT) atomicAdd(&h[pairs[bs + i] >> 20], 1);
        }
        __syncthreads();
        int v = 0, inc = 0;
        if (t < BSZ) {
            v = h[t];
            inc = v;
#pragma unroll
            for (int o = 1; o < 64; o <<= 1) {
                int n = __shfl_up(inc, o);
                if (lane >= o) inc += n;
            }
            if (lane == 63) wtot[w] = inc;   // waves 0,1 only
        }
        __syncthreads();
        if (t < BSZ) {
            int excl = ((w == 1) ? wtot[0] : 0) + inc - v;
            int node = (bb << BSH) + t;
            if (node < N) {
                rowstart[node] = bs + excl;
                zd[node].z = rsqrtf((float)(v + 1));
            }
            h[t] = excl;                     // bucket-relative scatter cursor
        }
        __syncthreads();
        if (fits) {
            for (int i = t; i < ne; i += KT) {
                unsigned p = stage[i];
                int pos = bs + atomicAdd(&h[p >> 20], 1);
                csr[pos] = (int)(p & 0xFFFFFu);
            }
        } else {
            for (int i = t; i < ne; i += KT) {
                unsigned p = pairs[bs + i];
                int pos = bs + atomicAdd(&h[p >> 20], 1);
                csr[pos] = (int)(p & 0xFFFFFu);
            }
        }
        __syncthreads();
    }

    // ---- z = x @ W12, one wave per node row (writes zd.xy; .z disjoint) ----
    int nwaves = B * (KT >> 6);
    int wid = b * (KT >> 6) + w;
    float4 wv = *(const float4*)(W12 + lane * 4);
    for (int node = wid; node < N; node += nwaves) {
        float2 xv = *(const float2*)(x + (size_t)node * D + lane * 2);
        float p0 = fmaf(xv.x, wv.x, xv.y * wv.z);
        float p1 = fmaf(xv.x, wv.y, xv.y * wv.w);
#pragma unroll
        for (int o = 32; o > 0; o >>= 1) {
            p0 += __shfl_xor(p0, o);
            p1 += __shfl_xor(p1, o);
        }
        if (lane == 0) {
            float2 r; r.x = p0; r.y = p1;
            *(float2*)&zd[node] = r;
        }
    }
}

// ---- K5: gather A (16 lanes/node, register acc) -> aw = (w*a1x, w*a1y, srow, w) ----
__global__ void k_gatherA(const int* __restrict__ csr, const int* __restrict__ rowstart,
                          const float4* __restrict__ zd, float4* __restrict__ aw, int N) {
    int g = blockIdx.x * blockDim.x + threadIdx.x;
    int node = g >> 4, lane = threadIdx.x & 15;
    if (node >= N) return;
    int rs = rowstart[node], re = rowstart[node + 1];
    float acc0 = 0.f, acc1 = 0.f, sw = 0.f;
    for (int j = rs + lane; j < re; j += 16) {
        int s = csr[j];
        float4 zv = zd[s];                     // (z0, z1, dinv, -)
        acc0 = fmaf(zv.z, zv.x, acc0);
        acc1 = fmaf(zv.z, zv.y, acc1);
        sw  += zv.z;
    }
#pragma unroll
    for (int o = 8; o > 0; o >>= 1) {
        acc0 += __shfl_xor(acc0, o);
        acc1 += __shfl_xor(acc1, o);
        sw   += __shfl_xor(sw, o);
    }
    if (lane == 0) {
        float4 zv = zd[node];
        float wd = zv.z;
        float a1x  = wd * (acc0 + wd * zv.x);
        float a1y  = wd * (acc1 + wd * zv.y);
        float srow = wd * (sw + wd);
        aw[node] = make_float4(wd * a1x, wd * a1y, srow, wd);
    }
}

// ---- K6: gather B (16 lanes/node) + rank-1 bias + gumbel softmax epilogue ----
__global__ void k_gatherB(const int* __restrict__ csr, const int* __restrict__ rowstart,
                          const float4* __restrict__ aw, const float* __restrict__ cvec,
                          const float* __restrict__ b2, const float2* __restrict__ noise,
                          float2* __restrict__ out, int N) {
    int g = blockIdx.x * blockDim.x + threadIdx.x;
    int node = g >> 4, lane = threadIdx.x & 15;
    if (node >= N) return;
    int rs = rowstart[node], re = rowstart[node + 1];
    float acc0 = 0.f, acc1 = 0.f;
    for (int j = rs + lane; j < re; j += 16) {
        int s = csr[j];
        float4 av = aw[s];                     // (w*a1x, w*a1y, srow, w)
        acc0 += av.x;
        acc1 += av.y;
    }
#pragma unroll
    for (int o = 8; o > 0; o >>= 1) {
        acc0 += __shfl_xor(acc0, o);
        acc1 += __shfl_xor(acc1, o);
    }
    if (lane == 0) {
        float4 av = aw[node];
        float wd = av.w;
        float l0 = wd * (acc0 + av.x) + av.z * cvec[0] + b2[0];
        float l1 = wd * (acc1 + av.y) + av.z * cvec[1] + b2[1];
        const float EPS = 1e-9f;
        float2 nv = noise[node];
        float g0 = -logf(-logf(nv.x + EPS) + EPS);
        float g1 = -logf(-logf(nv.y + EPS) + EPS);
        float u0 = (l0 + g0) * 2.0f;
        float u1 = (l1 + g1) * 2.0f;
        float m = fmaxf(u0, u1);
        float e0 = __expf(u0 - m), e1 = __expf(u1 - m);
        float inv = 1.0f / (e0 + e1);
        float2 r; r.x = e0 * inv; r.y = e1 * inv;
        out[node] = r;
    }
}

extern "C" void kernel_launch(void* const* d_in, const int* in_sizes, int n_in,
                              void* d_out, int out_size, void* d_ws, size_t ws_size,
                              hipStream_t stream) {
    const float* x     = (const float*)d_in[0];
    const int*   ei    = (const int*)d_in[1];
    const float* W1    = (const float*)d_in[2];
    const float* b1    = (const float*)d_in[3];
    const float* W2    = (const float*)d_in[4];
    const float* b2    = (const float*)d_in[5];
    const float* noise = (const float*)d_in[6];
    float* out = (float*)d_out;

    const int N = in_sizes[0] / D;
    const int E = in_sizes[1] / 2;
    const int* src = ei;
    const int* dst = ei + E;
    const int NB = (N + BSZ - 1) >> BSH;       // buckets of 128 nodes (<=512)

    // ---- workspace carve (16B-aligned chunks first) ----
    char* p = (char*)d_ws;
    float4*   zd       = (float4*)p;   p += (size_t)N * 16;
    float4*   aw       = (float4*)p;   p += (size_t)N * 16;
    unsigned* pairs    = (unsigned*)p; p += (size_t)E * 4;
    int*      csr      = (int*)p;      p += (size_t)E * 4;
    int*      rowstart = (int*)p;      p += (size_t)(N + 4) * 4;
    int*      hist_t   = (int*)p;      p += (size_t)512 * GB1 * 4;   // 1 MB
    int*      dsum     = (int*)p;      p += 512 * 4;
    float*    W12      = (float*)p;    p += 256 * 4;
    float*    cvec     = (float*)p;    p += 16;

    int g16 = (N * 16 + 255) / 256;            // 16 lanes/node, 256-thr blocks

    k_hist<<<GB1, KT, 0, stream>>>(dst, hist_t, W1, b1, W2, W12, cvec, E, NB);
    k_scan_digit<<<NB, KT, 0, stream>>>(hist_t, dsum, rowstart, N, E);
    k_scatter_pairs<<<GB1, KT, 0, stream>>>(src, dst, hist_t, dsum, pairs, E, NB);
    k_csr_z<<<1024, KT, 0, stream>>>(pairs, dsum, x, W12, csr, rowstart, zd, N, E, NB);
    k_gatherA<<<g16, 256, 0, stream>>>(csr, rowstart, zd, aw, N);
    k_gatherB<<<g16, 256, 0, stream>>>(csr, rowstart, aw, cvec, b2, (const float2*)noise,
                                       (float2*)out, N);
}